// Round 1
// baseline (186.535 us; speedup 1.0000x reference)
//
#include <hip/hip_runtime.h>

#define WW 320          // input width/height
#define OWID 314        // output cols
#define OHEI 314        // output rows
#define BB 64           // batch
#define RPB 8           // output rows per band (16 -> 8: 2x waves, occupancy was the bottleneck)
#define NBAND 40        // ceil(314/8)
#define NSTRIP 79       // ceil(314/4) output-col strips of 4
#define NTH 256
#define NBLK ((BB * NBAND * NSTRIP) / NTH)   // 64*40*79/256 = 790 exactly

// Compute the 4 horizontal 7-tap sums of the 5 channel-combined moments for
// one input row. h[q*4+j] for moment q in {sx,sy,sxx,syy,sxy}, output col j.
__device__ __forceinline__ void compute_h(
    const float* __restrict__ X0, const float* __restrict__ X1,
    const float* __restrict__ Y0, const float* __restrict__ Y1,
    int off, int o2, float h[20])
{
    float4 ax0 = *(const float4*)(X0 + off);
    float4 ax1 = *(const float4*)(X0 + off + 4);
    float4 ax2 = *(const float4*)(X0 + off + o2);
    float4 bx0 = *(const float4*)(X1 + off);
    float4 bx1 = *(const float4*)(X1 + off + 4);
    float4 bx2 = *(const float4*)(X1 + off + o2);
    float4 ay0 = *(const float4*)(Y0 + off);
    float4 ay1 = *(const float4*)(Y0 + off + 4);
    float4 ay2 = *(const float4*)(Y0 + off + o2);
    float4 by0 = *(const float4*)(Y1 + off);
    float4 by1 = *(const float4*)(Y1 + off + 4);
    float4 by2 = *(const float4*)(Y1 + off + o2);

    float x0[10] = {ax0.x, ax0.y, ax0.z, ax0.w, ax1.x, ax1.y, ax1.z, ax1.w, ax2.x, ax2.y};
    float x1[10] = {bx0.x, bx0.y, bx0.z, bx0.w, bx1.x, bx1.y, bx1.z, bx1.w, bx2.x, bx2.y};
    float y0[10] = {ay0.x, ay0.y, ay0.z, ay0.w, ay1.x, ay1.y, ay1.z, ay1.w, ay2.x, ay2.y};
    float y1[10] = {by0.x, by0.y, by0.z, by0.w, by1.x, by1.y, by1.z, by1.w, by2.x, by2.y};

    float sx[10], sy[10], sxx[10], syy[10], sxy[10];
    #pragma unroll
    for (int j = 0; j < 10; ++j) {
        sx[j]  = x0[j] + x1[j];
        sy[j]  = y0[j] + y1[j];
        sxx[j] = x0[j] * x0[j] + x1[j] * x1[j];
        syy[j] = y0[j] * y0[j] + y1[j] * y1[j];
        sxy[j] = x0[j] * y0[j] + x1[j] * y1[j];
    }
    #pragma unroll
    for (int q = 0; q < 5; ++q) {
        const float* m = (q == 0) ? sx : (q == 1) ? sy : (q == 2) ? sxx : (q == 3) ? syy : sxy;
        float t0 = ((m[0] + m[1]) + (m[2] + m[3])) + ((m[4] + m[5]) + m[6]);
        float t1 = t0 - m[0] + m[7];
        float t2 = t1 - m[1] + m[8];
        float t3 = t2 - m[2] + m[9];
        h[q * 4 + 0] = t0; h[q * 4 + 1] = t1; h[q * 4 + 2] = t2; h[q * 4 + 3] = t3;
    }
}

__global__ __launch_bounds__(NTH) void ssim_main(
    const float* __restrict__ X, const float* __restrict__ Y,
    const float* __restrict__ dr, double* __restrict__ acc,
    unsigned* __restrict__ counter, float* __restrict__ out)
{
    const int wi   = blockIdx.x * NTH + threadIdx.x;   // grid sized exactly
    const int s    = wi % NSTRIP;
    const int g    = wi / NSTRIP;
    const int band = g % NBAND;
    const int b    = g / NBAND;
    const int r0   = band * RPB;
    const int r1   = min(r0 + RPB, OHEI);
    const int cb   = s * 4;
    const int o2   = (cb <= 308) ? 8 : 4;   // clamp 3rd float4 for last strip

    const size_t plane = (size_t)WW * WW;
    const float* X0 = X + (size_t)b * 2 * plane;
    const float* X1 = X0 + plane;
    const float* Y0 = Y + (size_t)b * 2 * plane;
    const float* Y1 = Y0 + plane;

    const float d  = dr[b];
    const float C1 = (0.01f * d) * (0.01f * d);
    const float C2 = (0.03f * d) * (0.03f * d);

    float cm[4];
    #pragma unroll
    for (int j = 0; j < 4; ++j) cm[j] = (cb + j < OWID) ? 1.0f : 0.0f;

    float v[20];
    #pragma unroll
    for (int i = 0; i < 20; ++i) v[i] = 0.0f;

    // warm-up: rows r0 .. r0+5
    for (int k = 0; k < 6; ++k) {
        float h[20];
        compute_h(X0, X1, Y0, Y1, (r0 + k) * WW + cb, o2, h);
        #pragma unroll
        for (int i = 0; i < 20; ++i) v[i] += h[i];
    }

    float ssum = 0.0f;
    for (int t = r0; t < r1; ++t) {
        // Issue BOTH row-loads (t+6 add-row, t sub-row) back-to-back so 24
        // dwordx4 loads are in flight before the dependent epilogue.
        float hn[20], ho[20];
        compute_h(X0, X1, Y0, Y1, (t + 6) * WW + cb, o2, hn);
        compute_h(X0, X1, Y0, Y1, t * WW + cb, o2, ho);

        #pragma unroll
        for (int i = 0; i < 20; ++i) v[i] += hn[i];

        const float inv = 1.0f / 49.0f;
        const float cn  = 49.0f / 48.0f;
        #pragma unroll
        for (int j = 0; j < 4; ++j) {
            float ux  = v[j]      * inv, uy  = v[4 + j]  * inv;
            float uxx = v[8 + j]  * inv, uyy = v[12 + j] * inv, uxy = v[16 + j] * inv;
            float vx  = cn * (uxx - ux * ux);
            float vy  = cn * (uyy - uy * uy);
            float vxy = cn * (uxy - ux * uy);
            float A1  = 2.0f * ux * uy + C1;
            float A2  = 2.0f * vxy + C2;
            float B1  = ux * ux + uy * uy + C1;
            float B2  = vx + vy + C2;
            ssum += cm[j] * (A1 * A2) / (B1 * B2);
        }

        #pragma unroll
        for (int i = 0; i < 20; ++i) v[i] -= ho[i];
    }

    // ---- reduction: wave shuffle (double) -> LDS -> one atomic per block ----
    double local = (double)ssum;
    #pragma unroll
    for (int off = 32; off > 0; off >>= 1)
        local += __shfl_down(local, off, 64);
    __shared__ double wsum[NTH / 64];
    const int lane = threadIdx.x & 63, wid = threadIdx.x >> 6;
    if (lane == 0) wsum[wid] = local;
    __syncthreads();
    if (threadIdx.x == 0) {
        double tot = (wsum[0] + wsum[1]) + (wsum[2] + wsum[3]);
        atomicAdd(acc, tot);
        __threadfence();
        unsigned ticket = atomicAdd(counter, 1u);
        if (ticket == NBLK - 1) {
            double stot = atomicAdd(acc, 0.0);   // device-scope coherent read
            const double N = (double)BB * (double)OHEI * (double)OWID;
            out[0] = (float)(1.0 - stot / N);
        }
    }
}

extern "C" void kernel_launch(void* const* d_in, const int* in_sizes, int n_in,
                              void* d_out, int out_size, void* d_ws, size_t ws_size,
                              hipStream_t stream)
{
    const float* X  = (const float*)d_in[0];
    const float* Y  = (const float*)d_in[1];
    const float* dr = (const float*)d_in[2];
    // d_in[3] is the box kernel w (all 1/49) — folded into constants.
    double*   acc     = (double*)d_ws;
    unsigned* counter = (unsigned*)((char*)d_ws + 8);
    float*    out     = (float*)d_out;

    hipMemsetAsync(d_ws, 0, 16, stream);
    ssim_main<<<dim3(NBLK), dim3(NTH), 0, stream>>>(X, Y, dr, acc, counter, out);
}

// Round 2
// 153.513 us; speedup vs baseline: 1.2151x; 1.2151x over previous
//
#include <hip/hip_runtime.h>

#define WW 320          // input width/height
#define OWID 314        // output cols
#define OHEI 314        // output rows
#define BB 64           // batch
#define RPB 28          // output rows per band (multiple of 7 for static ring slots)
#define NBAND 12        // ceil(314/28); last band row-masked
#define NSTRIP 79       // ceil(314/4) output-col strips of 4
#define NTH 256
#define NBLK ((BB * NBAND * NSTRIP) / NTH)   // 64*12*79/256 = 237 exactly (<=256 CUs: one round)

// Compute the 4 horizontal 7-tap sums of the 5 channel-combined moments for
// one input row. h[q*4+j] for moment q in {sx,sy,sxx,syy,sxy}, output col j.
__device__ __forceinline__ void compute_h(
    const float* __restrict__ X0, const float* __restrict__ X1,
    const float* __restrict__ Y0, const float* __restrict__ Y1,
    int off, int o2, float* __restrict__ h)
{
    float4 ax0 = *(const float4*)(X0 + off);
    float4 ax1 = *(const float4*)(X0 + off + 4);
    float4 ax2 = *(const float4*)(X0 + off + o2);
    float4 bx0 = *(const float4*)(X1 + off);
    float4 bx1 = *(const float4*)(X1 + off + 4);
    float4 bx2 = *(const float4*)(X1 + off + o2);
    float4 ay0 = *(const float4*)(Y0 + off);
    float4 ay1 = *(const float4*)(Y0 + off + 4);
    float4 ay2 = *(const float4*)(Y0 + off + o2);
    float4 by0 = *(const float4*)(Y1 + off);
    float4 by1 = *(const float4*)(Y1 + off + 4);
    float4 by2 = *(const float4*)(Y1 + off + o2);

    float x0[10] = {ax0.x, ax0.y, ax0.z, ax0.w, ax1.x, ax1.y, ax1.z, ax1.w, ax2.x, ax2.y};
    float x1[10] = {bx0.x, bx0.y, bx0.z, bx0.w, bx1.x, bx1.y, bx1.z, bx1.w, bx2.x, bx2.y};
    float y0[10] = {ay0.x, ay0.y, ay0.z, ay0.w, ay1.x, ay1.y, ay1.z, ay1.w, ay2.x, ay2.y};
    float y1[10] = {by0.x, by0.y, by0.z, by0.w, by1.x, by1.y, by1.z, by1.w, by2.x, by2.y};

    float sx[10], sy[10], sxx[10], syy[10], sxy[10];
    #pragma unroll
    for (int j = 0; j < 10; ++j) {
        sx[j]  = x0[j] + x1[j];
        sy[j]  = y0[j] + y1[j];
        sxx[j] = x0[j] * x0[j] + x1[j] * x1[j];
        syy[j] = y0[j] * y0[j] + y1[j] * y1[j];
        sxy[j] = x0[j] * y0[j] + x1[j] * y1[j];
    }
    #pragma unroll
    for (int q = 0; q < 5; ++q) {
        const float* m = (q == 0) ? sx : (q == 1) ? sy : (q == 2) ? sxx : (q == 3) ? syy : sxy;
        float t0 = ((m[0] + m[1]) + (m[2] + m[3])) + ((m[4] + m[5]) + m[6]);
        float t1 = t0 - m[0] + m[7];
        float t2 = t1 - m[1] + m[8];
        float t3 = t2 - m[2] + m[9];
        h[q * 4 + 0] = t0; h[q * 4 + 1] = t1; h[q * 4 + 2] = t2; h[q * 4 + 3] = t3;
    }
}

// __launch_bounds__(256, 1): 1 workgroup/CU — grid is 237 blocks so higher
// occupancy is unreachable anyway; unlock the VGPR budget for the 7-row ring.
__global__ __launch_bounds__(NTH, 1) void ssim_main(
    const float* __restrict__ X, const float* __restrict__ Y,
    const float* __restrict__ dr, double* __restrict__ acc,
    unsigned* __restrict__ counter, float* __restrict__ out)
{
    const int wi   = blockIdx.x * NTH + threadIdx.x;   // grid sized exactly
    const int s    = wi % NSTRIP;
    const int g    = wi / NSTRIP;
    const int band = g % NBAND;
    const int b    = g / NBAND;
    const int r0   = band * RPB;                        // multiple of 7
    const int cb   = s * 4;
    const int o2   = (cb <= 308) ? 8 : 4;   // clamp 3rd float4 for last strip

    const size_t plane = (size_t)WW * WW;
    const float* X0 = X + (size_t)b * 2 * plane;
    const float* X1 = X0 + plane;
    const float* Y0 = Y + (size_t)b * 2 * plane;
    const float* Y1 = Y0 + plane;

    const float d  = dr[b];
    const float C1 = (0.01f * d) * (0.01f * d);
    const float C2 = (0.03f * d) * (0.03f * d);

    float cm[4];
    #pragma unroll
    for (int j = 0; j < 4; ++j) cm[j] = (cb + j < OWID) ? 1.0f : 0.0f;

    // Ring of the last 7 rows' horizontal moment sums. All indices static
    // (RPB % 7 == 0 and full unroll) so this stays in registers.
    float ring[7][20];
    float v[20];
    #pragma unroll
    for (int i = 0; i < 20; ++i) v[i] = 0.0f;

    // warm-up: rows r0 .. r0+5 (always <= 313: in-bounds, no clamp needed)
    #pragma unroll
    for (int k = 0; k < 6; ++k) {
        compute_h(X0, X1, Y0, Y1, (r0 + k) * WW + cb, o2, &ring[k][0]);
        #pragma unroll
        for (int i = 0; i < 20; ++i) v[i] += ring[k][i];
    }

    float ssum = 0.0f;
    for (int t7 = 0; t7 < RPB; t7 += 7) {
        #pragma unroll
        for (int k = 0; k < 7; ++k) {
            const int t    = r0 + t7 + k;            // output row
            const int rin  = min(t + 6, WW - 1);     // clamp: tail-band rows masked below
            const int slot = (k + 6) % 7;            // static: row (t+6) mod 7

            compute_h(X0, X1, Y0, Y1, rin * WW + cb, o2, &ring[slot][0]);
            #pragma unroll
            for (int i = 0; i < 20; ++i) v[i] += ring[slot][i];

            if (t < OHEI) {                          // row mask (tail band only)
                const float inv = 1.0f / 49.0f;
                const float cn  = 49.0f / 48.0f;
                #pragma unroll
                for (int j = 0; j < 4; ++j) {
                    float ux  = v[j]      * inv, uy  = v[4 + j]  * inv;
                    float uxx = v[8 + j]  * inv, uyy = v[12 + j] * inv, uxy = v[16 + j] * inv;
                    float vx  = cn * (uxx - ux * ux);
                    float vy  = cn * (uyy - uy * uy);
                    float vxy = cn * (uxy - ux * uy);
                    float A1  = 2.0f * ux * uy + C1;
                    float A2  = 2.0f * vxy + C2;
                    float B1  = ux * ux + uy * uy + C1;
                    float B2  = vx + vy + C2;
                    ssum += cm[j] * (A1 * A2) / (B1 * B2);
                }
            }

            #pragma unroll
            for (int i = 0; i < 20; ++i) v[i] -= ring[k][i];   // expire row t
        }
    }

    // ---- reduction: wave shuffle (double) -> LDS -> one atomic per block ----
    double local = (double)ssum;
    #pragma unroll
    for (int off = 32; off > 0; off >>= 1)
        local += __shfl_down(local, off, 64);
    __shared__ double wsum[NTH / 64];
    const int lane = threadIdx.x & 63, wid = threadIdx.x >> 6;
    if (lane == 0) wsum[wid] = local;
    __syncthreads();
    if (threadIdx.x == 0) {
        double tot = (wsum[0] + wsum[1]) + (wsum[2] + wsum[3]);
        atomicAdd(acc, tot);
        __threadfence();
        unsigned ticket = atomicAdd(counter, 1u);
        if (ticket == NBLK - 1) {
            double stot = atomicAdd(acc, 0.0);   // device-scope coherent read
            const double N = (double)BB * (double)OHEI * (double)OWID;
            out[0] = (float)(1.0 - stot / N);
        }
    }
}

extern "C" void kernel_launch(void* const* d_in, const int* in_sizes, int n_in,
                              void* d_out, int out_size, void* d_ws, size_t ws_size,
                              hipStream_t stream)
{
    const float* X  = (const float*)d_in[0];
    const float* Y  = (const float*)d_in[1];
    const float* dr = (const float*)d_in[2];
    // d_in[3] is the box kernel w (all 1/49) — folded into constants.
    double*   acc     = (double*)d_ws;
    unsigned* counter = (unsigned*)((char*)d_ws + 8);
    float*    out     = (float*)d_out;

    hipMemsetAsync(d_ws, 0, 16, stream);
    ssim_main<<<dim3(NBLK), dim3(NTH), 0, stream>>>(X, Y, dr, acc, counter, out);
}

// Round 3
// 141.374 us; speedup vs baseline: 1.3194x; 1.0859x over previous
//
#include <hip/hip_runtime.h>

#define WW 320          // input width/height
#define OWID 314        // output cols
#define OHEI 314        // output rows
#define BB 64           // batch
#define RPB 28          // output rows per band (multiple of 7 for static ring slots)
#define NBAND 12        // ceil(314/28); last band row-masked
#define NSTRIP 79       // ceil(314/4) output-col strips of 4
#define NTH 256
#define NBLK ((BB * NBAND * NSTRIP) / NTH)   // 64*12*79/256 = 237 exactly (<=256 CUs: one round)

// Load exactly the 10 floats needed per plane: float4 + float4 + float2.
// o2 = 8 normally; 4 for the last strip (stays in-bounds; elems 8,9 then
// duplicate 4,5 and are masked by cm).
__device__ __forceinline__ void load_row(
    const float* __restrict__ X0, const float* __restrict__ X1,
    const float* __restrict__ Y0, const float* __restrict__ Y1,
    int off, int o2, float4 r4[8], float2 r2[4])
{
    r4[0] = *(const float4*)(X0 + off);
    r4[1] = *(const float4*)(X0 + off + 4);
    r2[0] = *(const float2*)(X0 + off + o2);
    r4[2] = *(const float4*)(X1 + off);
    r4[3] = *(const float4*)(X1 + off + 4);
    r2[1] = *(const float2*)(X1 + off + o2);
    r4[4] = *(const float4*)(Y0 + off);
    r4[5] = *(const float4*)(Y0 + off + 4);
    r2[2] = *(const float2*)(Y0 + off + o2);
    r4[6] = *(const float4*)(Y1 + off);
    r4[7] = *(const float4*)(Y1 + off + 4);
    r2[3] = *(const float2*)(Y1 + off + o2);
}

// The 4 horizontal 7-tap sums of the 5 channel-combined moments for one
// (already loaded) input row. h[q*4+j] for moment q in {sx,sy,sxx,syy,sxy}.
__device__ __forceinline__ void math_row(const float4 r4[8], const float2 r2[4], float h[20])
{
    float x0[10] = {r4[0].x, r4[0].y, r4[0].z, r4[0].w, r4[1].x, r4[1].y, r4[1].z, r4[1].w, r2[0].x, r2[0].y};
    float x1[10] = {r4[2].x, r4[2].y, r4[2].z, r4[2].w, r4[3].x, r4[3].y, r4[3].z, r4[3].w, r2[1].x, r2[1].y};
    float y0[10] = {r4[4].x, r4[4].y, r4[4].z, r4[4].w, r4[5].x, r4[5].y, r4[5].z, r4[5].w, r2[2].x, r2[2].y};
    float y1[10] = {r4[6].x, r4[6].y, r4[6].z, r4[6].w, r4[7].x, r4[7].y, r4[7].z, r4[7].w, r2[3].x, r2[3].y};

    float sx[10], sy[10], sxx[10], syy[10], sxy[10];
    #pragma unroll
    for (int j = 0; j < 10; ++j) {
        sx[j]  = x0[j] + x1[j];
        sy[j]  = y0[j] + y1[j];
        sxx[j] = x0[j] * x0[j] + x1[j] * x1[j];
        syy[j] = y0[j] * y0[j] + y1[j] * y1[j];
        sxy[j] = x0[j] * y0[j] + x1[j] * y1[j];
    }
    #pragma unroll
    for (int q = 0; q < 5; ++q) {
        const float* m = (q == 0) ? sx : (q == 1) ? sy : (q == 2) ? sxx : (q == 3) ? syy : sxy;
        float t0 = ((m[0] + m[1]) + (m[2] + m[3])) + ((m[4] + m[5]) + m[6]);
        float t1 = t0 - m[0] + m[7];
        float t2 = t1 - m[1] + m[8];
        float t3 = t2 - m[2] + m[9];
        h[q * 4 + 0] = t0; h[q * 4 + 1] = t1; h[q * 4 + 2] = t2; h[q * 4 + 3] = t3;
    }
}

// __launch_bounds__(256, 1): 1 workgroup/CU by design (grid = 237 <= 256 CUs,
// single round) — unlock the full VGPR budget for ring + double row buffer.
__global__ __launch_bounds__(NTH, 1) void ssim_main(
    const float* __restrict__ X, const float* __restrict__ Y,
    const float* __restrict__ dr, double* __restrict__ acc,
    unsigned* __restrict__ counter, float* __restrict__ out)
{
    const int wi   = blockIdx.x * NTH + threadIdx.x;   // grid sized exactly
    const int s    = wi % NSTRIP;
    const int g    = wi / NSTRIP;
    const int band = g % NBAND;
    const int b    = g / NBAND;
    const int r0   = band * RPB;                        // multiple of 7
    const int cb   = s * 4;
    const int o2   = (cb <= 308) ? 8 : 4;   // clamp tail strip in-bounds

    const size_t plane = (size_t)WW * WW;
    const float* X0 = X + (size_t)b * 2 * plane;
    const float* X1 = X0 + plane;
    const float* Y0 = Y + (size_t)b * 2 * plane;
    const float* Y1 = Y0 + plane;

    const float d  = dr[b];
    const float C1 = (0.01f * d) * (0.01f * d);
    const float C2 = (0.03f * d) * (0.03f * d);

    float cm[4];
    #pragma unroll
    for (int j = 0; j < 4; ++j) cm[j] = (cb + j < OWID) ? 1.0f : 0.0f;

    // Ring of the last 7 rows' h-sums; zero-init so the first 7 subtracts
    // are no-ops (uniform streaming body, no separate warm-up).
    float ring[7][20];
    #pragma unroll
    for (int k = 0; k < 7; ++k)
        #pragma unroll
        for (int q = 0; q < 20; ++q) ring[k][q] = 0.0f;

    float v[20];
    #pragma unroll
    for (int q = 0; q < 20; ++q) v[q] = 0.0f;

    // Depth-2 software pipeline: cur holds row r0+i, nxt is in flight.
    float4 c4[8], n4[8];
    float2 c2[4], n2[4];
    load_row(X0, X1, Y0, Y1, r0 * WW + cb, o2, c4, c2);

    float ssum = 0.0f;
    const float inv = 1.0f / 49.0f;
    const float cn  = 49.0f / 48.0f;

    // Stream 34 input rows (i = 0..33); i = 34 is a masked dead step so the
    // 7-wide unroll (static ring slots) divides evenly.
    for (int i7 = 0; i7 < 35; i7 += 7) {
        #pragma unroll
        for (int k = 0; k < 7; ++k) {
            const int i = i7 + k;

            if (i < 33) {                       // prefetch row r0+i+1
                const int rn = min(r0 + i + 1, WW - 1);   // clamp: tail band masked
                load_row(X0, X1, Y0, Y1, rn * WW + cb, o2, n4, n2);
            }
            if (i < 34) {
                float h[20];
                math_row(c4, c2, h);            // row r0+i (waits on cur loads;
                                                // nxt loads already in flight)
                #pragma unroll
                for (int q = 0; q < 20; ++q) {
                    v[q] += h[q] - ring[k][q];  // slot k == i mod 7 (static)
                    ring[k][q] = h[q];
                }

                const int t = r0 + i - 6;       // output row
                if (i >= 6 && t < OHEI) {
                    #pragma unroll
                    for (int j = 0; j < 4; ++j) {
                        float ux  = v[j]      * inv, uy  = v[4 + j]  * inv;
                        float uxx = v[8 + j]  * inv, uyy = v[12 + j] * inv, uxy = v[16 + j] * inv;
                        float vx  = cn * (uxx - ux * ux);
                        float vy  = cn * (uyy - uy * uy);
                        float vxy = cn * (uxy - ux * uy);
                        float A1  = 2.0f * ux * uy + C1;
                        float A2  = 2.0f * vxy + C2;
                        float B1  = ux * ux + uy * uy + C1;
                        float B2  = vx + vy + C2;
                        ssum += cm[j] * (A1 * A2) / (B1 * B2);
                    }
                }

                #pragma unroll
                for (int q = 0; q < 8; ++q) c4[q] = n4[q];   // rotate pipeline
                #pragma unroll
                for (int q = 0; q < 4; ++q) c2[q] = n2[q];
            }
        }
    }

    // ---- reduction: wave shuffle (double) -> LDS -> one atomic per block ----
    double local = (double)ssum;
    #pragma unroll
    for (int off = 32; off > 0; off >>= 1)
        local += __shfl_down(local, off, 64);
    __shared__ double wsum[NTH / 64];
    const int lane = threadIdx.x & 63, wid = threadIdx.x >> 6;
    if (lane == 0) wsum[wid] = local;
    __syncthreads();
    if (threadIdx.x == 0) {
        double tot = (wsum[0] + wsum[1]) + (wsum[2] + wsum[3]);
        atomicAdd(acc, tot);
        __threadfence();
        unsigned ticket = atomicAdd(counter, 1u);
        if (ticket == NBLK - 1) {
            double stot = atomicAdd(acc, 0.0);   // device-scope coherent read
            const double N = (double)BB * (double)OHEI * (double)OWID;
            out[0] = (float)(1.0 - stot / N);
        }
    }
}

extern "C" void kernel_launch(void* const* d_in, const int* in_sizes, int n_in,
                              void* d_out, int out_size, void* d_ws, size_t ws_size,
                              hipStream_t stream)
{
    const float* X  = (const float*)d_in[0];
    const float* Y  = (const float*)d_in[1];
    const float* dr = (const float*)d_in[2];
    // d_in[3] is the box kernel w (all 1/49) — folded into constants.
    double*   acc     = (double*)d_ws;
    unsigned* counter = (unsigned*)((char*)d_ws + 8);
    float*    out     = (float*)d_out;

    hipMemsetAsync(d_ws, 0, 16, stream);
    ssim_main<<<dim3(NBLK), dim3(NTH), 0, stream>>>(X, Y, dr, acc, counter, out);
}